// Round 3
// baseline (327.399 us; speedup 1.0000x reference)
//
#include <hip/hip_runtime.h>
#include <hip/hip_bf16.h>
#include <math.h>

typedef __bf16 bf16_8 __attribute__((ext_vector_type(8)));
typedef float f32x4 __attribute__((ext_vector_type(4)));

#define NDIM 1024
#define BATCH 32
#define MAT_ELEMS (NDIM * NDIM)
#define BSTRIDE 40  // B tile LDS row stride (80 B = 20 banks -> 2-way max)

__device__ static inline void async_copy16(const void* g, void* l) {
  __builtin_amdgcn_global_load_lds(
      (__attribute__((address_space(1))) void*)g,
      (__attribute__((address_space(3))) void*)l, 16, 0, 0);
}

// C[k][j] = s(k) * cos(pi * k * (2j+1) / 2048), s(0)=1/32, s(k)=sqrt(2)/32
__global__ void gen_dct_mat(__bf16* __restrict__ C) {
  int idx = blockIdx.x * blockDim.x + threadIdx.x;
  int k = idx >> 10;
  int j = idx & 1023;
  int t = (k * (2 * j + 1)) & 4095;  // exact phase reduction mod 2*pi
  float ang = (float)t * 1.5339807878856412e-3f;  // pi/2048
  float s = (k == 0) ? 0.03125f : 0.04419417382415922f;
  C[idx] = (__bf16)(s * cosf(ang));
}

// Fused: out[b] = Cmat @ x[b].  A (Cmat) staged via swizzled global_load_lds
// double-buffered; B (x) transposed+converted in-flight with register prefetch.
__global__ __launch_bounds__(256) void dct_fused(
    const float* __restrict__ x, const __bf16* __restrict__ A,
    float* __restrict__ out) {
  __shared__ __align__(64) __bf16 Asm[2][128 * 32];   // 2 x 8 KB, 64 B rows
  __shared__ __align__(64) __bf16 Bsm[128 * BSTRIDE]; // 10 KB

  const int t = threadIdx.x;
  const int wave = t >> 6;
  const int lane = t & 63;
  const int bb = blockIdx.z;
  const int m0 = blockIdx.y * 128;
  const int n0 = blockIdx.x * 128;

  // --- A DMA, xor-swizzled: DMA writes lane l at base + l*16 -> physical
  // chunk p=l&3 of row r=l>>2 (per 64-row issue). Load logical chunk
  // c = p ^ ((r>>1)&3) = (l&3) ^ ((l>>3)&3) so banks spread on reads.
  const int asw = ((lane & 3) ^ ((lane >> 3) & 3)) * 8;  // elements
  const __bf16* Ag0 =
      A + (size_t)(m0 + wave * 16 + (lane >> 2)) * NDIM + asw;
  const __bf16* Ag1 = Ag0 + (size_t)64 * NDIM;
  const int al0 = (wave * 16) * 32;
  const int al1 = (64 + wave * 16) * 32;

  // --- B staging: thread t covers col c = n0+(t&127), rows k0+(t>>7)*16+q.
  // Reads are lane-coalesced (256 B/row-instr); cvt+ds_write per iter.
  const int bc = t & 127;
  const int bjg = t >> 7;
  const float* xs =
      x + (size_t)bb * MAT_ELEMS + (size_t)(bjg * 16) * NDIM + (n0 + bc);
  bf16_8* bs0 = (bf16_8*)(Bsm + bc * BSTRIDE + bjg * 16);
  bf16_8* bs1 = (bf16_8*)(Bsm + bc * BSTRIDE + bjg * 16 + 8);

  // --- fragment read offsets
  const int row16 = lane & 15;
  // A physical chunk for logical chunk l>>4 at row (..+(l&15)):
  const int aksw = ((lane >> 4) ^ ((lane >> 1) & 3)) * 8;  // elements
  const int kq8 = (lane >> 4) * 8;  // B: no swizzle (padded stride)
  const int wm = (wave & 1) * 64;
  const int wn = (wave >> 1) * 64;

  f32x4 acc[4][4] = {};

  // prologue: prefetch iter 0 (latency exposed once)
  async_copy16(Ag0, (__bf16*)Asm[0] + al0);
  async_copy16(Ag1, (__bf16*)Asm[0] + al1);
  float f[16];
#pragma unroll
  for (int q = 0; q < 16; q++) f[q] = xs[(size_t)q * NDIM];

  for (int k0 = 0; k0 < NDIM; k0 += 32) {
    const int buf = (k0 >> 5) & 1;
    // barrier1: prior iter's LDS reads done; compiler's vmcnt(0) drain here
    // covers A-DMA(k)/B-loads(k) issued BEFORE last iter's MFMA block.
    __syncthreads();
    bf16_8 v0, v1;
#pragma unroll
    for (int q = 0; q < 8; q++) {
      v0[q] = (__bf16)f[q];
      v1[q] = (__bf16)f[q + 8];
    }
    *bs0 = v0;
    *bs1 = v1;
    __syncthreads();  // barrier2: only ds_write lgkm to drain (cheap)

    // prefetch iter k+1 (wrapped on last iter to stay in-bounds; results
    // drained at next barrier1, hidden behind the MFMA block below)
    const int kn = (k0 + 32) & (NDIM - 1);
    async_copy16(Ag0 + kn, (__bf16*)Asm[buf ^ 1] + al0);
    async_copy16(Ag1 + kn, (__bf16*)Asm[buf ^ 1] + al1);
    const float* xp = xs + (size_t)kn * NDIM;
#pragma unroll
    for (int q = 0; q < 16; q++) f[q] = xp[(size_t)q * NDIM];

    const __bf16* Ab = (const __bf16*)Asm[buf];
    bf16_8 af[4], bfr[4];
#pragma unroll
    for (int i = 0; i < 4; i++)
      af[i] = *(const bf16_8*)(Ab + (wm + i * 16 + row16) * 32 + aksw);
#pragma unroll
    for (int j = 0; j < 4; j++)
      bfr[j] = *(const bf16_8*)(Bsm + (wn + j * 16 + row16) * BSTRIDE + kq8);
#pragma unroll
    for (int i = 0; i < 4; i++)
#pragma unroll
      for (int j = 0; j < 4; j++)
        acc[i][j] = __builtin_amdgcn_mfma_f32_16x16x32_bf16(af[i], bfr[j],
                                                            acc[i][j], 0, 0, 0);
  }

  // epilogue: C/D layout col = lane&15, row = (lane>>4)*4 + reg
  float* ob = out + (size_t)bb * MAT_ELEMS;
  const int rbase = (lane >> 4) * 4;
  const int cofs = lane & 15;
#pragma unroll
  for (int i = 0; i < 4; i++) {
#pragma unroll
    for (int r = 0; r < 4; r++) {
      int row = m0 + wm + i * 16 + rbase + r;
#pragma unroll
      for (int j = 0; j < 4; j++) {
        int col = n0 + wn + j * 16 + cofs;
        ob[(size_t)row * NDIM + col] = acc[i][j][r];
      }
    }
  }
}

extern "C" void kernel_launch(void* const* d_in, const int* in_sizes, int n_in,
                              void* d_out, int out_size, void* d_ws,
                              size_t ws_size, hipStream_t stream) {
  const float* x = (const float*)d_in[0];
  float* out = (float*)d_out;
  __bf16* Cmat = (__bf16*)d_ws;  // 2 MB

  gen_dct_mat<<<dim3(MAT_ELEMS / 256), dim3(256), 0, stream>>>(Cmat);
  dct_fused<<<dim3(8, 8, BATCH), dim3(256), 0, stream>>>(x, Cmat, out);
}